// Round 13
// baseline (86.769 us; speedup 1.0000x reference)
//
#include <hip/hip_runtime.h>
#include <math.h>

#define M_BATCH 8
#define NC 1024
#define NTGT 512
#define G_DIM 129
#define NG (G_DIM * G_DIM)        // 16641
#define N_OUT (G_DIM * 3)         // 387
#define MROWS 160                 // padded A rows (5*32)
#define NROWS 416                 // padded B rows (13*32)
#define MT_TILES 5
#define NT_TILES 13
#define LDA 136                   // padded LDS row stride (halves) = 272 B
#define TILE (32 * LDA)           // halves per staged tile

typedef __attribute__((ext_vector_type(8))) _Float16 half8;
typedef __attribute__((ext_vector_type(4))) float floatx4;

#if defined(__has_builtin)
#if __has_builtin(__builtin_amdgcn_exp2f)
#define FAST_EXP2(x) __builtin_amdgcn_exp2f(x)
#endif
#endif
#ifndef FAST_EXP2
#define FAST_EXP2(x) exp2f(x)
#endif

// ---------- Kernel 1: minmax -> meta (xmid, scales); write x_grid ----------
__global__ __launch_bounds__(256) void prep_kernel(
        const float* __restrict__ xc, const float* __restrict__ xt,
        const float* __restrict__ lsp,
        float* __restrict__ meta,       // [0..15]=xmid(m,2), [16]=s0, [17]=s1
        float* __restrict__ out_grid) {
    const int tid = threadIdx.x;
    const int chunk = blockIdx.x;      // 16 chunks share x_grid writing
    const int m = blockIdx.y;

    float mn0 = 1e30f, mx0 = -1e30f, mn1 = 1e30f, mx1 = -1e30f;
    const float2* pc = (const float2*)(xc + m * NC * 2);
    for (int i = tid; i < NC; i += 256) {
        float2 p = pc[i];
        mn0 = fminf(mn0, p.x); mx0 = fmaxf(mx0, p.x);
        mn1 = fminf(mn1, p.y); mx1 = fmaxf(mx1, p.y);
    }
    const float2* pt = (const float2*)(xt + m * NTGT * 2);
    for (int i = tid; i < NTGT; i += 256) {
        float2 p = pt[i];
        mn0 = fminf(mn0, p.x); mx0 = fmaxf(mx0, p.x);
        mn1 = fminf(mn1, p.y); mx1 = fmaxf(mx1, p.y);
    }
    __shared__ float4 sm[256];
    sm[tid] = make_float4(mn0, mx0, mn1, mx1);
    __syncthreads();
    for (int s = 128; s > 0; s >>= 1) {
        if (tid < s) {
            float4 a = sm[tid], b = sm[tid + s];
            sm[tid] = make_float4(fminf(a.x, b.x), fmaxf(a.y, b.y),
                                  fminf(a.z, b.z), fmaxf(a.w, b.w));
        }
        __syncthreads();
    }
    const float mid0 = 0.5f * (sm[0].x + sm[0].y);
    const float mid1 = 0.5f * (sm[0].z + sm[0].w);
    if (chunk == 0 && tid == 0) {
        meta[m * 2 + 0] = mid0;
        meta[m * 2 + 1] = mid1;
        if (m == 0) {
            const float Kc = 0.84932180028801904272f;  // sqrt(0.5*log2(e))
            const float ls0 = 1e-5f + log1pf(expf(lsp[0]));
            const float ls1 = 1e-5f + log1pf(expf(lsp[1]));
            meta[16] = Kc / ls0;
            meta[17] = Kc / ls1;
        }
    }

    const float inv_ppu = 1.0f / 64.0f;
    float2* og = (float2*)out_grid + (size_t)m * NG;
    const int per = (NG + 16 * 256 - 1) / (16 * 256);
    for (int r = 0; r < per; ++r) {
        const int g = (chunk * per + r) * 256 + tid;
        if (g < NG) {
            const int ix = g / G_DIM;
            const int iy = g - ix * G_DIM;
            og[g] = make_float2(mid0 + (float)(ix - 64) * inv_ppu,
                                mid1 + (float)(iy - 64) * inv_ppu);
        }
    }
}

// ---------- Kernel 2: build unique weight matrices (fp16, K-contiguous) ----
// A[m][r][c] = exp2(-((gx(r)-cx_c)*s0)^2)            r<129, else 0
// B[m][n][c] = exp2(-((gy(iy)-cy_c)*s1)^2) * ych     n=3*iy+ch <387, else 0
// One thread writes one half8 (8 consecutive c).
__global__ __launch_bounds__(256) void build_kernel(
        const float* __restrict__ xc, const float* __restrict__ yc,
        const float* __restrict__ meta,
        half8* __restrict__ Ah, half8* __restrict__ Bh) {
    const int idx = blockIdx.x * 256 + threadIdx.x;
    const float inv_ppu = 1.0f / 64.0f;
    const int totalA = M_BATCH * MROWS * (NC / 8);

    if (idx < totalA) {
        const int kb = idx & 127;
        const int rest = idx >> 7;
        const int r = rest % MROWS;
        const int m = rest / MROWS;
        half8 out;
        if (r < G_DIM) {
            const float s0 = meta[16];
            const float gxs = (meta[m * 2 + 0] + (float)(r - 64) * inv_ppu) * s0;
            const float4* xc4 = (const float4*)(xc + m * NC * 2) + kb * 4;
#pragma unroll
            for (int h = 0; h < 4; ++h) {
                const float4 xq = xc4[h];
                const float d0 = fmaf(-xq.x, s0, gxs);
                const float d1 = fmaf(-xq.z, s0, gxs);
                out[2 * h + 0] = (_Float16)FAST_EXP2(-(d0 * d0));
                out[2 * h + 1] = (_Float16)FAST_EXP2(-(d1 * d1));
            }
        } else {
            out = (half8){0, 0, 0, 0, 0, 0, 0, 0};
        }
        Ah[idx] = out;
    } else {
        const int j = idx - totalA;
        if (j >= M_BATCH * NROWS * (NC / 8)) return;
        const int kb = j & 127;
        const int rest = j >> 7;
        const int n = rest % NROWS;
        const int m = rest / NROWS;
        half8 out;
        if (n < N_OUT) {
            const int iy = (int)(((unsigned)n * 0xAAABu) >> 17);
            const int ch = n - 3 * iy;
            const float s1 = meta[17];
            const float gys = (meta[m * 2 + 1] + (float)(iy - 64) * inv_ppu) * s1;
            const float4* xc4 = (const float4*)(xc + m * NC * 2) + kb * 4;
            const float4* yc4 = (const float4*)(yc + m * NC * 2) + kb * 4;
#pragma unroll
            for (int h = 0; h < 4; ++h) {
                const float4 xq = xc4[h];
                const float4 yq = yc4[h];
                const float d0 = fmaf(-xq.y, s1, gys);
                const float d1 = fmaf(-xq.w, s1, gys);
                const float w0 = FAST_EXP2(-(d0 * d0));
                const float w1 = FAST_EXP2(-(d1 * d1));
                const float ya = (ch == 0) ? yq.x : (ch == 1) ? yq.y : 1.0f;
                const float yb = (ch == 0) ? yq.z : (ch == 1) ? yq.w : 1.0f;
                out[2 * h + 0] = (_Float16)(w0 * ya);
                out[2 * h + 1] = (_Float16)(w1 * yb);
            }
        } else {
            out = (half8){0, 0, 0, 0, 0, 0, 0, 0};
        }
        Bh[j] = out;
    }
}

// ---------- Kernel 3: LDS-tiled GEMM. Block = 32x32 tile, 4 waves ----------
// Staging per chunk: 32 rows x 128 halves per tile = 512 half8; 256 threads
// copy TWO half8 per tile (jb*8 and jb*8+64). [R12 bug: only one was copied.]
__global__ __launch_bounds__(256) void gemm_kernel(
        const _Float16* __restrict__ Ah, const _Float16* __restrict__ Bh,
        float* __restrict__ out_z) {
    const int tid = threadIdx.x;
    const int nt = blockIdx.x;
    const int mt = blockIdx.y;
    const int m  = blockIdx.z;

    __shared__ __align__(16) _Float16 lds[4 * TILE];   // A0 B0 A1 B1

    const int row = tid >> 3;          // 0..31
    const int jb  = tid & 7;           // 16B block within first half-row
    const _Float16* asrc = Ah + ((size_t)(m * MROWS + mt * 32 + row) * NC) + jb * 8;
    const _Float16* bsrc = Bh + ((size_t)(m * NROWS + nt * 32 + row) * NC) + jb * 8;
    _Float16* adst = lds + row * LDA + jb * 8;         // + buf*2*TILE
    _Float16* bdst = lds + TILE + row * LDA + jb * 8;  // + buf*2*TILE

    const int w = tid >> 6;
    const int wm = w >> 1;
    const int wn = w & 1;
    const int lane = tid & 63;
    const int ln = lane & 15;
    const int q = lane >> 4;

    floatx4 acc = {0.f, 0.f, 0.f, 0.f};

    // stage chunk 0 into buf 0 (two half8 per tile per thread)
    *(half8*)adst        = *(const half8*)asrc;
    *(half8*)(adst + 64) = *(const half8*)(asrc + 64);
    *(half8*)bdst        = *(const half8*)bsrc;
    *(half8*)(bdst + 64) = *(const half8*)(bsrc + 64);
    __syncthreads();

    for (int kc = 0; kc < 8; ++kc) {
        const int buf = kc & 1;
        const _Float16* Ab = lds + buf * 2 * TILE;
        const _Float16* Bb = lds + buf * 2 * TILE + TILE;
#pragma unroll
        for (int kk = 0; kk < 4; ++kk) {
            half8 a = *(const half8*)&Ab[(wm * 16 + ln) * LDA + kk * 32 + q * 8];
            half8 b = *(const half8*)&Bb[(wn * 16 + ln) * LDA + kk * 32 + q * 8];
            acc = __builtin_amdgcn_mfma_f32_16x16x32_f16(a, b, acc, 0, 0, 0);
        }
        if (kc + 1 < 8) {
            const int off = (kc + 1) * 128;
            const int nbo = ((kc + 1) & 1) * 2 * TILE;
            *(half8*)(adst + nbo)      = *(const half8*)(asrc + off);
            *(half8*)(adst + nbo + 64) = *(const half8*)(asrc + off + 64);
            *(half8*)(bdst + nbo)      = *(const half8*)(bsrc + off);
            *(half8*)(bdst + nbo + 64) = *(const half8*)(bsrc + off + 64);
        }
        __syncthreads();
    }

    const int ngo = nt * 32 + wn * 16 + ln;
    if (ngo < N_OUT) {
        float* oz = out_z + (size_t)m * NG * 3;
        const int ixb = mt * 32 + wm * 16 + q * 4;
#pragma unroll
        for (int rr = 0; rr < 4; ++rr) {
            const int ixg = ixb + rr;
            if (ixg < G_DIM) oz[(size_t)ixg * N_OUT + ngo] = acc[rr];
        }
    }
}

extern "C" void kernel_launch(void* const* d_in, const int* in_sizes, int n_in,
                              void* d_out, int out_size, void* d_ws, size_t ws_size,
                              hipStream_t stream) {
    const float* xc  = (const float*)d_in[0];
    const float* yc  = (const float*)d_in[1];
    const float* xt  = (const float*)d_in[2];
    const float* lsp = (const float*)d_in[3];

    float* out_grid = (float*)d_out;
    float* out_z = out_grid + (size_t)M_BATCH * NG * 2;

    float* meta = (float*)d_ws;
    _Float16* Ah = (_Float16*)((char*)d_ws + 256);
    _Float16* Bh = (_Float16*)((char*)d_ws + 256 +
                               (size_t)M_BATCH * MROWS * NC * 2);

    dim3 gprep(16, M_BATCH);
    prep_kernel<<<gprep, 256, 0, stream>>>(xc, xt, lsp, meta, out_grid);

    const int totalAB = M_BATCH * (MROWS + NROWS) * (NC / 8);   // 589,824
    build_kernel<<<totalAB / 256, 256, 0, stream>>>(xc, yc, meta,
                                                    (half8*)Ah, (half8*)Bh);

    dim3 ggemm(NT_TILES, MT_TILES, M_BATCH);   // (13, 5, 8)
    gemm_kernel<<<ggemm, 256, 0, stream>>>(Ah, Bh, out_z);
}

// Round 14
// 67.824 us; speedup vs baseline: 1.2793x; 1.2793x over previous
//
#include <hip/hip_runtime.h>
#include <math.h>

#define M_BATCH 8
#define NC 1024
#define NTGT 512
#define G_DIM 129
#define NG (G_DIM * G_DIM)        // 16641
#define N_OUT (G_DIM * 3)         // 387
#define TM 32                     // ix per block
#define TIY 32                    // iy per block
#define KCH 128
#define NKCH (NC / KCH)           // 8
#define LDA 136                   // padded LDS row stride (halves)
#define ABYTES (TM * LDA * 2)     // 8704
#define BUFBYTES (2 * ABYTES + 512)   // A + Wy + ye(256) + yo(256) = 17920
#define GT 5                      // tiles per dim (5*32=160 >= 129)

typedef __attribute__((ext_vector_type(8))) _Float16 half8;
typedef __attribute__((ext_vector_type(2))) _Float16 half2v;
typedef __attribute__((ext_vector_type(4))) float floatx4;

#if defined(__has_builtin)
#if __has_builtin(__builtin_amdgcn_exp2f)
#define FAST_EXP2(x) __builtin_amdgcn_exp2f(x)
#endif
#endif
#ifndef FAST_EXP2
#define FAST_EXP2(x) exp2f(x)
#endif

// Block = 32ix x 32iy x 3ch of batch m. 512 threads = 8 waves =
// 2x2 spatial subtiles x 2 K-groups. Per chunk stage A=wx (32x128),
// Wy (32x128), ye/yo (128 halves each) in LDS (double-buffered, 1 barrier
// per chunk); per k-step each wave: 3 MFMAs sharing one A-frag and one
// Wy-frag (ch0 = wy*ye, ch1 = wy*yo, ch2 = wy). Cross-Kgroup reduce in LDS.
__global__ __launch_bounds__(512) void fused_kernel(
        const float* __restrict__ xc, const float* __restrict__ yc,
        const float* __restrict__ xt, const float* __restrict__ lsp,
        float* __restrict__ out_grid, float* __restrict__ out_z) {
    const int tid = threadIdx.x;
    const int iyt = blockIdx.x;        // 0..4
    const int mt = blockIdx.y;         // 0..4
    const int m  = blockIdx.z;

    __shared__ __align__(16) char lds_raw[2 * BUFBYTES];   // 35840 B

    // ---- Phase 1: minmax over concat(xc[m], xt[m]) ----
    {
        float mn0 = 1e30f, mx0 = -1e30f, mn1 = 1e30f, mx1 = -1e30f;
        const float2* pc = (const float2*)(xc + m * NC * 2);
        for (int i = tid; i < NC; i += 512) {
            float2 p = pc[i];
            mn0 = fminf(mn0, p.x); mx0 = fmaxf(mx0, p.x);
            mn1 = fminf(mn1, p.y); mx1 = fmaxf(mx1, p.y);
        }
        const float2* pt = (const float2*)(xt + m * NTGT * 2);
        {
            float2 p = pt[tid];
            mn0 = fminf(mn0, p.x); mx0 = fmaxf(mx0, p.x);
            mn1 = fminf(mn1, p.y); mx1 = fmaxf(mx1, p.y);
        }
        ((float4*)lds_raw)[tid] = make_float4(mn0, mx0, mn1, mx1);
    }
    __syncthreads();
    {
        float4* sm = (float4*)lds_raw;
        for (int s = 256; s > 0; s >>= 1) {
            if (tid < s) {
                float4 a = sm[tid], b = sm[tid + s];
                sm[tid] = make_float4(fminf(a.x, b.x), fmaxf(a.y, b.y),
                                      fminf(a.z, b.z), fmaxf(a.w, b.w));
            }
            __syncthreads();
        }
    }
    const float mid0 = 0.5f * (((float4*)lds_raw)[0].x + ((float4*)lds_raw)[0].y);
    const float mid1 = 0.5f * (((float4*)lds_raw)[0].z + ((float4*)lds_raw)[0].w);
    __syncthreads();

    const float Kc = 0.84932180028801904272f;  // sqrt(0.5*log2(e))
    const float ls0 = 1e-5f + log1pf(expf(lsp[0]));
    const float ls1 = 1e-5f + log1pf(expf(lsp[1]));
    const float s0 = Kc / ls0, s1 = Kc / ls1;
    const float inv_ppu = 1.0f / 64.0f;

    // ---- Phase 2: x_grid rows of this mt (iyt==0 blocks) ----
    if (iyt == 0) {
        const int r0 = mt * TM;
        const int nrows = min(TM, G_DIM - r0);
        float2* og = (float2*)out_grid + (size_t)m * NG;
        for (int g = tid; g < nrows * G_DIM; g += 512) {
            const int r = g / G_DIM;
            const int iyy = g - r * G_DIM;
            const int ixg = r0 + r;
            og[(size_t)ixg * G_DIM + iyy] =
                make_float2(mid0 + (float)(ixg - 64) * inv_ppu,
                            mid1 + (float)(iyy - 64) * inv_ppu);
        }
    }

    // ---- staging setup ----
    const int c2 = (tid & 63) * 2;        // local c pair
    const int r0s = tid >> 6;             // row slot base (rows r0s+8i)
    const float4* xc4 = (const float4*)(xc + m * NC * 2);
    const float4* yc4 = (const float4*)(yc + m * NC * 2);
    const float gxs_base = (mid0 + (float)(mt * TM - 64) * inv_ppu) * s0;
    const float gys_base = (mid1 + (float)(iyt * TIY - 64) * inv_ppu) * s1;
    const float gstep_x = inv_ppu * s0;
    const float gstep_y = inv_ppu * s1;

    // ---- wave mapping: 8 waves = (g, wm, wn) ----
    const int w = tid >> 6;
    const int g = w >> 2;                 // K-group 0/1
    const int wm = (w >> 1) & 1;
    const int wn = w & 1;
    const int lane = tid & 63;
    const int ln = lane & 15;
    const int q = lane >> 4;

    floatx4 acc0 = {0.f, 0.f, 0.f, 0.f};
    floatx4 acc1 = {0.f, 0.f, 0.f, 0.f};
    floatx4 acc2 = {0.f, 0.f, 0.f, 0.f};

    auto stage = [&](int kc, int buf) {
        const int cp = kc * 64 + (tid & 63);
        const float4 xq = xc4[cp];
        const float4 yq = yc4[cp];
        const float cx0 = xq.x * s0, cx1 = xq.z * s0;
        const float cy0 = xq.y * s1, cy1 = xq.w * s1;
        _Float16* Ab  = (_Float16*)(lds_raw + buf * BUFBYTES);
        _Float16* Wyb = (_Float16*)(lds_raw + buf * BUFBYTES + ABYTES);
        _Float16* yeb = (_Float16*)(lds_raw + buf * BUFBYTES + 2 * ABYTES);
        _Float16* yob = yeb + 128;
#pragma unroll
        for (int i = 0; i < 4; ++i) {
            const int r = r0s + 8 * i;
            const float gxs = gxs_base + (float)r * gstep_x;
            const float dx0 = gxs - cx0;
            const float dx1 = gxs - cx1;
            *(half2v*)&Ab[r * LDA + c2] =
                (half2v){(_Float16)FAST_EXP2(-(dx0 * dx0)),
                         (_Float16)FAST_EXP2(-(dx1 * dx1))};
            const float gys = gys_base + (float)r * gstep_y;
            const float dy0 = gys - cy0;
            const float dy1 = gys - cy1;
            *(half2v*)&Wyb[r * LDA + c2] =
                (half2v){(_Float16)FAST_EXP2(-(dy0 * dy0)),
                         (_Float16)FAST_EXP2(-(dy1 * dy1))};
        }
        if (tid < 64) {
            *(half2v*)&yeb[c2] = (half2v){(_Float16)yq.x, (_Float16)yq.z};
            *(half2v*)&yob[c2] = (half2v){(_Float16)yq.y, (_Float16)yq.w};
        }
    };

    stage(0, 0);
    __syncthreads();

    for (int kc = 0; kc < NKCH; ++kc) {
        const int buf = kc & 1;
        const _Float16* Ab  = (const _Float16*)(lds_raw + buf * BUFBYTES);
        const _Float16* Wyb = (const _Float16*)(lds_raw + buf * BUFBYTES + ABYTES);
        const _Float16* yeb = (const _Float16*)(lds_raw + buf * BUFBYTES + 2 * ABYTES);
#pragma unroll
        for (int kk = 0; kk < 2; ++kk) {
            const int off = g * 64 + kk * 32 + q * 8;
            half8 a  = *(const half8*)&Ab[(wm * 16 + ln) * LDA + off];
            half8 wy = *(const half8*)&Wyb[(wn * 16 + ln) * LDA + off];
            half8 ye = *(const half8*)&yeb[off];
            half8 yo = *(const half8*)&yeb[128 + off];
            acc2 = __builtin_amdgcn_mfma_f32_16x16x32_f16(a, wy, acc2, 0, 0, 0);
            acc0 = __builtin_amdgcn_mfma_f32_16x16x32_f16(a, wy * ye, acc0, 0, 0, 0);
            acc1 = __builtin_amdgcn_mfma_f32_16x16x32_f16(a, wy * yo, acc1, 0, 0, 0);
        }
        if (kc + 1 < NKCH) stage(kc + 1, buf ^ 1);
        __syncthreads();
    }

    // ---- cross-Kgroup reduction: g==1 writes, g==0 adds + stores ----
    floatx4* cs = (floatx4*)lds_raw;       // [4 spatial][3 ch][64 lanes] = 12 KB
    const int ws = wm * 2 + wn;
    if (g == 1) {
        cs[(ws * 3 + 0) * 64 + lane] = acc0;
        cs[(ws * 3 + 1) * 64 + lane] = acc1;
        cs[(ws * 3 + 2) * 64 + lane] = acc2;
    }
    __syncthreads();
    if (g == 0) {
        const floatx4 o0 = cs[(ws * 3 + 0) * 64 + lane];
        const floatx4 o1 = cs[(ws * 3 + 1) * 64 + lane];
        const floatx4 o2 = cs[(ws * 3 + 2) * 64 + lane];
        const int iyg = iyt * TIY + wn * 16 + ln;
        if (iyg < G_DIM) {
            float* oz = out_z + (size_t)m * NG * 3 + (size_t)iyg * 3;
            const int ixb = mt * TM + wm * 16 + q * 4;
#pragma unroll
            for (int rr = 0; rr < 4; ++rr) {
                const int ixg = ixb + rr;
                if (ixg < G_DIM) {
                    float* p = oz + (size_t)ixg * N_OUT;
                    p[0] = acc0[rr] + o0[rr];
                    p[1] = acc1[rr] + o1[rr];
                    p[2] = acc2[rr] + o2[rr];
                }
            }
        }
    }
}

extern "C" void kernel_launch(void* const* d_in, const int* in_sizes, int n_in,
                              void* d_out, int out_size, void* d_ws, size_t ws_size,
                              hipStream_t stream) {
    const float* xc  = (const float*)d_in[0];
    const float* yc  = (const float*)d_in[1];
    const float* xt  = (const float*)d_in[2];
    const float* lsp = (const float*)d_in[3];

    float* out_grid = (float*)d_out;
    float* out_z = out_grid + (size_t)M_BATCH * NG * 2;

    dim3 grid(GT, GT, M_BATCH);   // (5, 5, 8) = 200 blocks x 512 threads
    fused_kernel<<<grid, 512, 0, stream>>>(xc, yc, xt, lsp, out_grid, out_z);
}